// Round 13
// baseline (200.631 us; speedup 1.0000x reference)
//
#include <hip/hip_runtime.h>
#include <math.h>

#define N_NODES 100000
#define N_EDGES 1600000
#define D_FEAT 32
#define D_HID 64
#define D_OUT 64
#define CAP 48          // per-node slot capacity; deg ~ Poisson(16), safe
#define NPB 32          // nodes per coarse bucket (1<<5); 3125*32 = 100000 exact
#define NBKT 3125       // N_NODES / NPB
#define B1 256          // sort blocks; each owns a dense 6250-entry segment
#define E_PER_B1 6250   // 256 * 6250 = 1.6M edges exactly
#define NTILE 64        // node-precompute tile (64 nodes staged in LDS)
#define NB_NODE 1563    // ceil(100000/64) node tiles, one block each

typedef _Float16 half8 __attribute__((ext_vector_type(8)));
typedef float f32x16 __attribute__((ext_vector_type(16)));

// packed f16 relu(v + (-q)) on a channel pair, guaranteed lowering:
// exactly one v_pk_add_f16 + one v_pk_max_f16.
__device__ inline unsigned pk_subrelu(unsigned v, unsigned nq) {
    unsigned r;
    asm("v_pk_add_f16 %0, %1, %2\n\t"
        "v_pk_max_f16 %0, %0, 0"
        : "=v"(r) : "v"(v), "v"(nq));
    return r;
}

// ---------------------------------------------------------------------------
// Kernel 1: per-node precompute (R11-identical; f32 math, f16 store, q
// NEGATED). 64-node x/pos tiles staged into LDS with coalesced loads; the
// per-node x reads are LDS broadcasts instead of 35 serial uniform VMEM ops.
// ---------------------------------------------------------------------------
__global__ __launch_bounds__(256)
void node_kernel(const float* __restrict__ x,
                 const float* __restrict__ pos,
                 const float* __restrict__ W1,
                 const float* __restrict__ b1,
                 unsigned short* __restrict__ vb,
                 unsigned short* __restrict__ qb) {
    __shared__ float xs[NTILE * D_FEAT];   // 8 KB
    __shared__ float ps[NTILE * 3];        // 768 B

    const int tid  = threadIdx.x;
    const int lane = tid & 63;
    const int wave = tid >> 6;

    const int n0  = blockIdx.x * NTILE;
    const int cnt = (N_NODES - n0 < NTILE) ? (N_NODES - n0) : NTILE;  // 64 or 32

    for (int i = tid; i < cnt * D_FEAT; i += 256)
        xs[i] = x[(size_t)n0 * D_FEAT + i];
    for (int i = tid; i < cnt * 3; i += 256)
        ps[i] = pos[(size_t)n0 * 3 + i];

    float w[D_FEAT + 3];
#pragma unroll
    for (int f = 0; f < D_FEAT + 3; ++f)
        w[f] = W1[f * D_HID + lane];
    const float bb = b1[lane];
    __syncthreads();

    for (int ln = wave; ln < cnt; ln += 4) {
        const int node = n0 + ln;
        float acc = bb;
#pragma unroll
        for (int f = 0; f < D_FEAT; ++f)
            acc = fmaf(xs[ln * D_FEAT + f], w[f], acc);   // LDS broadcast reads

        float qa = 0.0f;
#pragma unroll
        for (int p = 0; p < 3; ++p)
            qa = fmaf(ps[ln * 3 + p], w[D_FEAT + p], qa);

        vb[(size_t)node * D_HID + lane] =
            __builtin_bit_cast(unsigned short, (_Float16)(acc + qa));
        qb[(size_t)node * D_HID + lane] =
            __builtin_bit_cast(unsigned short, (_Float16)(-qa));
    }
}

// ---------------------------------------------------------------------------
// Kernel 2: dense local counting sort + W2T build (block 0) — R11 version
// (3-pass with LDS stage + dense copy-out; R12's single-pass variant was
// neutral-to-worse: sort cost is latency phases, not global passes).
// Entry packing: (src << 5) | (dst & 31).
// ---------------------------------------------------------------------------
__global__ __launch_bounds__(1024)
void sort_kernel(const int* __restrict__ src,
                 const int* __restrict__ dst,
                 unsigned int* __restrict__ coarse,
                 int* __restrict__ dir,
                 const float* __restrict__ W2,
                 unsigned short* __restrict__ W2T) {
    __shared__ int hist[NBKT];       // 12.5 KB: counts -> starts -> cursors
    __shared__ int stage[E_PER_B1];  // 25 KB
    __shared__ int wsum[16];

    const int tid  = threadIdx.x;
    const int lane = tid & 63;
    const int wv   = tid >> 6;       // 0..15
    const int e0   = blockIdx.x * E_PER_B1;

    if (blockIdx.x == 0) {           // f16 transpose of W2 (16 KB, L2-hot)
        for (int i = tid; i < D_HID * D_OUT; i += 1024) {
            float w = W2[i];                      // i = k*64 + n
            W2T[(size_t)(i & 63) * D_HID + (i >> 6)] =
                __builtin_bit_cast(unsigned short, (_Float16)w);
        }
    }

    for (int b = tid; b < NBKT; b += 1024) hist[b] = 0;
    __syncthreads();

    for (int e = e0 + tid; e < e0 + E_PER_B1; e += 1024)
        atomicAdd(&hist[dst[e] >> 5], 1);
    __syncthreads();

    // ---- exclusive scan of hist (3125) in place: 4 elems/thread ----
    const int i0 = tid * 4;
    int c[4];
    int sum = 0;
#pragma unroll
    for (int k = 0; k < 4; ++k) {
        c[k] = (i0 + k < NBKT) ? hist[i0 + k] : 0;
        sum += c[k];
    }
    int inc = sum;                       // wave-inclusive scan of chunk sums
#pragma unroll
    for (int d = 1; d < 64; d <<= 1) {
        int u = __shfl_up(inc, d, 64);
        if (lane >= d) inc += u;
    }
    if (lane == 63) wsum[wv] = inc;      // wave totals
    __syncthreads();
    if (wv == 0) {
        int s = (lane < 16) ? wsum[lane] : 0;
#pragma unroll
        for (int d = 1; d < 16; d <<= 1) {
            int u = __shfl_up(s, d, 64);
            if (lane >= d) s += u;
        }
        if (lane < 16) wsum[lane] = s;   // inclusive wave prefix
    }
    __syncthreads();
    int excl = inc - sum + ((wv > 0) ? wsum[wv - 1] : 0);
#pragma unroll
    for (int k = 0; k < 4; ++k) {
        if (i0 + k < NBKT) hist[i0 + k] = excl;   // own slots only: no race
        excl += c[k];
    }
    __syncthreads();

    // ---- dense directory: absolute start of each bucket in this segment
    for (int b = tid; b < NBKT; b += 1024)
        dir[(size_t)blockIdx.x * NBKT + b] = e0 + hist[b];
    __syncthreads();                     // dir written before cursors move

    // ---- placement via LDS cursors into LDS staging ----
    for (int e = e0 + tid; e < e0 + E_PER_B1; e += 1024) {
        int d = dst[e], s = src[e];
        int p = atomicAdd(&hist[d >> 5], 1);   // p in [0, 6250) by construction
        stage[p] = (int)(((unsigned)s << 5) | (unsigned)(d & 31));
    }
    __syncthreads();

    // ---- dense, full-line copy-out ----
    for (int i = tid; i < E_PER_B1; i += 1024)
        coarse[e0 + i] = (unsigned)stage[i];
}

// ---------------------------------------------------------------------------
// Kernel 3: fused fine-bucketing + per-node MFMA aggregation, now on
// mfma_f32_32x32x16_f16. R12 lesson: agg is bound by DEPENDENT GATHER
// ROUNDS per node (2 batches of 16 rows, each a serial LDS->VMEM->compute
// chain; dur insensitive to VALU/occupancy/issue-order; FETCH 128MB =
// random gathers missing per-XCD L2). The 32x32 shape makes one batch
// cover deg<=31 (99.97% of nodes): A row = lane&31, K-chunk = (lane>>5)*8
// -> per node ONE round of 8 independent 16B loads (4 v + 4 nq), and 8
// MFMAs per 32 rows instead of 16. C/D: col=lane&31, 16 regs + lane-half
// hold the 32 rows -> max = 16 fmax + shfl_xor(32); coalesced 1-float
// store per lane. Padding rows use src = i (self-loop, idempotent under
// max; uniform address -> broadcast, nearly free).
// ---------------------------------------------------------------------------
__global__ __launch_bounds__(256)
void agg_kernel(const unsigned short* __restrict__ vb,
                const unsigned short* __restrict__ qb,
                const unsigned short* __restrict__ W2T,
                const float* __restrict__ b2,
                const int* __restrict__ dir,
                const unsigned int* __restrict__ coarse,
                float* __restrict__ out) {
    __shared__ int lcnt[NPB];
    __shared__ int lslots[NPB][CAP];

    const int tid  = threadIdx.x;
    const int lane = tid & 63;
    const int wave = tid >> 6;             // 0..3
    const int col  = lane & 31;            // A-row / C-col index
    const int half = lane >> 5;            // K-chunk selector
    const int bkt  = blockIdx.x;
    const int nbase = bkt << 5;

    // B fragments: bfrag[t][k] = W2T[t*32+col][k*16 + half*8 .. +8] (16B loads)
    half8 bfrag[2][4];
#pragma unroll
    for (int t = 0; t < 2; ++t)
#pragma unroll
        for (int k = 0; k < 4; ++k)
            bfrag[t][k] = *(const half8*)(W2T + (size_t)(t * 32 + col) * D_HID
                                               + k * 16 + half * 8);
    const float bias0 = b2[col];
    const float bias1 = b2[32 + col];

    // fine bucketing into LDS: thread t walks sort-block t's segment.
    for (int i = tid; i < NPB; i += 256) lcnt[i] = 0;
    __syncthreads();
    {
        const int s0 = dir[(size_t)tid * NBKT + bkt];
        const int s1 = (bkt + 1 < NBKT) ? dir[(size_t)tid * NBKT + bkt + 1]
                                        : (tid + 1) * E_PER_B1;
        for (int j = s0; j < s1; ++j) {
            unsigned enc = coarse[j];
            int local = (int)(enc & 31u);
            int s     = (int)(enc >> 5);
            int p = atomicAdd(&lcnt[local], 1);
            if (p < CAP) lslots[local][p] = s;
        }
    }
    __syncthreads();

    // per-node aggregation, 8 nodes per wave
    for (int ln = wave; ln < NPB; ln += 4) {
        const int node = nbase + ln;       // 3125*32 == N_NODES: no bound check

        uint4 nq[4];
#pragma unroll
        for (int k = 0; k < 4; ++k)
            nq[k] = *(const uint4*)(qb + (size_t)node * D_HID + k * 16 + half * 8);

        int deg = lcnt[ln];
        if (deg > CAP) deg = CAP;
        const int rows = deg + 1;              // + self-loop
        const int nbat = (rows + 31) >> 5;     // 1 for deg<=31 (99.97%)

        f32x16 rmax[2];
#pragma unroll
        for (int t = 0; t < 2; ++t)
#pragma unroll
            for (int r = 0; r < 16; ++r) rmax[t][r] = -INFINITY;

        for (int b = 0; b < nbat; ++b) {
            const int idx  = b * 32 + col;
            const int idxc = (idx < CAP) ? idx : (CAP - 1);    // clamp LDS read
            const int s = (idx < deg) ? lslots[ln][idxc] : node;

            uint4 vv[4];
#pragma unroll
            for (int k = 0; k < 4; ++k)
                vv[k] = *(const uint4*)(vb + (size_t)s * D_HID + k * 16 + half * 8);

            half8 a[4];
#pragma unroll
            for (int k = 0; k < 4; ++k) {
                uint4 au;
                au.x = pk_subrelu(vv[k].x, nq[k].x);
                au.y = pk_subrelu(vv[k].y, nq[k].y);
                au.z = pk_subrelu(vv[k].z, nq[k].z);
                au.w = pk_subrelu(vv[k].w, nq[k].w);
                a[k] = __builtin_bit_cast(half8, au);
            }

#pragma unroll
            for (int t = 0; t < 2; ++t) {
                f32x16 acc = {};
                acc = __builtin_amdgcn_mfma_f32_32x32x16_f16(a[0], bfrag[t][0], acc, 0, 0, 0);
                acc = __builtin_amdgcn_mfma_f32_32x32x16_f16(a[1], bfrag[t][1], acc, 0, 0, 0);
                acc = __builtin_amdgcn_mfma_f32_32x32x16_f16(a[2], bfrag[t][2], acc, 0, 0, 0);
                acc = __builtin_amdgcn_mfma_f32_32x32x16_f16(a[3], bfrag[t][3], acc, 0, 0, 0);
#pragma unroll
                for (int r = 0; r < 16; ++r)
                    rmax[t][r] = fmaxf(rmax[t][r], acc[r]);
            }
        }

        // reduce: 16 regs (rows within lane-half) + shfl_xor(32) (other half)
        float fin[2];
#pragma unroll
        for (int t = 0; t < 2; ++t) {
            float m = rmax[t][0];
#pragma unroll
            for (int r = 1; r < 16; ++r) m = fmaxf(m, rmax[t][r]);
            m = fmaxf(m, __shfl_xor(m, 32, 64));
            fin[t] = m + ((t == 0) ? bias0 : bias1);
        }
        out[(size_t)node * D_OUT + half * 32 + col] = half ? fin[1] : fin[0];
    }
}

// ---------------------------------------------------------------------------
extern "C" void kernel_launch(void* const* d_in, const int* in_sizes, int n_in,
                              void* d_out, int out_size, void* d_ws, size_t ws_size,
                              hipStream_t stream) {
    const float* x   = (const float*)d_in[0];
    const float* pos = (const float*)d_in[1];
    const int*   ei  = (const int*)d_in[2];   // [2][N_EDGES]: row0=src, row1=dst
    const float* W1  = (const float*)d_in[3];
    const float* b1  = (const float*)d_in[4];
    const float* W2  = (const float*)d_in[5];
    const float* b2  = (const float*)d_in[6];
    float* out = (float*)d_out;

    char* ws = (char*)d_ws;
    unsigned short* vb   = (unsigned short*)ws;                     // 12.8 MB (f16 v)
    unsigned short* qb   = (unsigned short*)(ws + 12800000);        // 12.8 MB (f16 -q)
    unsigned int* coarse = (unsigned int*)(ws + 25600000);          // 6.4 MB
    int*            dir  = (int*)(ws + 32000000);                   // 3.2 MB
    unsigned short* W2T  = (unsigned short*)(ws + 35200000);        // 8 KB (f16, transposed)

    const int* src = ei;
    const int* dst = ei + N_EDGES;

    hipLaunchKernelGGL(sort_kernel, dim3(B1), dim3(1024), 0, stream,
                       src, dst, coarse, dir, W2, W2T);
    hipLaunchKernelGGL(node_kernel, dim3(NB_NODE), dim3(256), 0, stream,
                       x, pos, W1, b1, vb, qb);
    hipLaunchKernelGGL(agg_kernel, dim3(NBKT), dim3(256), 0, stream,
                       vb, qb, W2T, b2, dir, coarse, out);
}

// Round 14
// 189.130 us; speedup vs baseline: 1.0608x; 1.0608x over previous
//
#include <hip/hip_runtime.h>
#include <math.h>

#define N_NODES 100000
#define N_EDGES 1600000
#define D_FEAT 32
#define D_HID 64
#define D_OUT 64
#define CAP 48          // per-node slot capacity; deg ~ Poisson(16), safe
#define NPB 32          // nodes per coarse bucket (1<<5); 3125*32 = 100000 exact
#define NBKT 3125       // N_NODES / NPB
#define B1 512          // sort blocks; 512 x 3125 = 1.6M edges exactly.
                        // R13 lesson: 256 blocks x 16 waves at the 32-wave/CU
                        // cap = 2 blocks/CU -> only 128 CUs covered. 512
                        // blocks cover all 256 CUs, half the latency rounds.
#define E_PER_B1 3125
#define NTILE 64        // node-precompute tile (64 nodes staged in LDS)
#define NB_NODE 1563    // ceil(100000/64) node tiles, one block each

typedef _Float16 half8 __attribute__((ext_vector_type(8)));
typedef float f32x4  __attribute__((ext_vector_type(4)));

// packed f16 relu(v + (-q)) on a channel pair, guaranteed lowering:
// exactly one v_pk_add_f16 + one v_pk_max_f16.
__device__ inline unsigned pk_subrelu(unsigned v, unsigned nq) {
    unsigned r;
    asm("v_pk_add_f16 %0, %1, %2\n\t"
        "v_pk_max_f16 %0, %0, 0"
        : "=v"(r) : "v"(v), "v"(nq));
    return r;
}

// ---------------------------------------------------------------------------
// Kernel 1: per-node precompute (R11-identical; f32 math, f16 store, q
// NEGATED). 64-node x/pos tiles staged into LDS with coalesced loads; the
// per-node x reads are LDS broadcasts instead of 35 serial uniform VMEM ops.
// ---------------------------------------------------------------------------
__global__ __launch_bounds__(256)
void node_kernel(const float* __restrict__ x,
                 const float* __restrict__ pos,
                 const float* __restrict__ W1,
                 const float* __restrict__ b1,
                 unsigned short* __restrict__ vb,
                 unsigned short* __restrict__ qb) {
    __shared__ float xs[NTILE * D_FEAT];   // 8 KB
    __shared__ float ps[NTILE * 3];        // 768 B

    const int tid  = threadIdx.x;
    const int lane = tid & 63;
    const int wave = tid >> 6;

    const int n0  = blockIdx.x * NTILE;
    const int cnt = (N_NODES - n0 < NTILE) ? (N_NODES - n0) : NTILE;  // 64 or 32

    for (int i = tid; i < cnt * D_FEAT; i += 256)
        xs[i] = x[(size_t)n0 * D_FEAT + i];
    for (int i = tid; i < cnt * 3; i += 256)
        ps[i] = pos[(size_t)n0 * 3 + i];

    float w[D_FEAT + 3];
#pragma unroll
    for (int f = 0; f < D_FEAT + 3; ++f)
        w[f] = W1[f * D_HID + lane];
    const float bb = b1[lane];
    __syncthreads();

    for (int ln = wave; ln < cnt; ln += 4) {
        const int node = n0 + ln;
        float acc = bb;
#pragma unroll
        for (int f = 0; f < D_FEAT; ++f)
            acc = fmaf(xs[ln * D_FEAT + f], w[f], acc);   // LDS broadcast reads

        float qa = 0.0f;
#pragma unroll
        for (int p = 0; p < 3; ++p)
            qa = fmaf(ps[ln * 3 + p], w[D_FEAT + p], qa);

        vb[(size_t)node * D_HID + lane] =
            __builtin_bit_cast(unsigned short, (_Float16)(acc + qa));
        qb[(size_t)node * D_HID + lane] =
            __builtin_bit_cast(unsigned short, (_Float16)(-qa));
    }
}

// ---------------------------------------------------------------------------
// Kernel 2: dense local counting sort + W2T build (block 0) — R11 structure
// at 512-block granularity (full CU coverage, 3 latency rounds per phase
// instead of 6). Entry packing: (src << 5) | (dst & 31).
// ---------------------------------------------------------------------------
__global__ __launch_bounds__(1024)
void sort_kernel(const int* __restrict__ src,
                 const int* __restrict__ dst,
                 unsigned int* __restrict__ coarse,
                 int* __restrict__ dir,
                 const float* __restrict__ W2,
                 unsigned short* __restrict__ W2T) {
    __shared__ int hist[NBKT];       // 12.5 KB: counts -> starts -> cursors
    __shared__ int stage[E_PER_B1];  // 12.5 KB
    __shared__ int wsum[16];

    const int tid  = threadIdx.x;
    const int lane = tid & 63;
    const int wv   = tid >> 6;       // 0..15
    const int e0   = blockIdx.x * E_PER_B1;

    if (blockIdx.x == 0) {           // f16 transpose of W2 (16 KB, L2-hot)
        for (int i = tid; i < D_HID * D_OUT; i += 1024) {
            float w = W2[i];                      // i = k*64 + n
            W2T[(size_t)(i & 63) * D_HID + (i >> 6)] =
                __builtin_bit_cast(unsigned short, (_Float16)w);
        }
    }

    for (int b = tid; b < NBKT; b += 1024) hist[b] = 0;
    __syncthreads();

    for (int e = e0 + tid; e < e0 + E_PER_B1; e += 1024)
        atomicAdd(&hist[dst[e] >> 5], 1);
    __syncthreads();

    // ---- exclusive scan of hist (3125) in place: 4 elems/thread ----
    const int i0 = tid * 4;
    int c[4];
    int sum = 0;
#pragma unroll
    for (int k = 0; k < 4; ++k) {
        c[k] = (i0 + k < NBKT) ? hist[i0 + k] : 0;
        sum += c[k];
    }
    int inc = sum;                       // wave-inclusive scan of chunk sums
#pragma unroll
    for (int d = 1; d < 64; d <<= 1) {
        int u = __shfl_up(inc, d, 64);
        if (lane >= d) inc += u;
    }
    if (lane == 63) wsum[wv] = inc;      // wave totals
    __syncthreads();
    if (wv == 0) {
        int s = (lane < 16) ? wsum[lane] : 0;
#pragma unroll
        for (int d = 1; d < 16; d <<= 1) {
            int u = __shfl_up(s, d, 64);
            if (lane >= d) s += u;
        }
        if (lane < 16) wsum[lane] = s;   // inclusive wave prefix
    }
    __syncthreads();
    int excl = inc - sum + ((wv > 0) ? wsum[wv - 1] : 0);
#pragma unroll
    for (int k = 0; k < 4; ++k) {
        if (i0 + k < NBKT) hist[i0 + k] = excl;   // own slots only: no race
        excl += c[k];
    }
    __syncthreads();

    // ---- dense directory: absolute start of each bucket in this segment
    for (int b = tid; b < NBKT; b += 1024)
        dir[(size_t)blockIdx.x * NBKT + b] = e0 + hist[b];
    __syncthreads();                     // dir written before cursors move

    // ---- placement via LDS cursors into LDS staging ----
    for (int e = e0 + tid; e < e0 + E_PER_B1; e += 1024) {
        int d = dst[e], s = src[e];
        int p = atomicAdd(&hist[d >> 5], 1);   // p in [0, 3125) by construction
        stage[p] = (int)(((unsigned)s << 5) | (unsigned)(d & 31));
    }
    __syncthreads();

    // ---- dense, full-line copy-out ----
    for (int i = tid; i < E_PER_B1; i += 1024)
        coarse[e0 + i] = (unsigned)stage[i];
}

// ---------------------------------------------------------------------------
// Kernel 3: fused fine-bucketing + per-node MFMA aggregation — R11-exact
// (R13's 32x32 variant reverted: it forced 32 row-slots/node vs the 16x16
// expected 24.5, +30% gather/VALU work, 100us vs 82). 3125 blocks of 256
// thr, 8 nodes/wave, W2T vector prologue, packed-f16 afrag, 4x2
// mfma_f32_16x16x32_f16, register max, coalesced store. Padding rows use
// src = i (self-loop, idempotent under max). Only delta: segment walk
// covers B1=512 segments (2 per thread).
// ---------------------------------------------------------------------------
__global__ __launch_bounds__(256)
void agg_kernel(const unsigned short* __restrict__ vb,
                const unsigned short* __restrict__ qb,
                const unsigned short* __restrict__ W2T,
                const float* __restrict__ b2,
                const int* __restrict__ dir,
                const unsigned int* __restrict__ coarse,
                float* __restrict__ out) {
    __shared__ int lcnt[NPB];
    __shared__ int lslots[NPB][CAP];

    const int tid  = threadIdx.x;
    const int lane = tid & 63;
    const int wave = tid >> 6;             // 0..3
    const int quad = lane >> 4;
    const int mrow = lane & 15;
    const int bkt  = blockIdx.x;
    const int nbase = bkt << 5;

    // B fragments: one 16B vector load each from W2T[n][k]
    half8 bfrag[4][2];
#pragma unroll
    for (int t = 0; t < 4; ++t)
#pragma unroll
        for (int kh = 0; kh < 2; ++kh)
            bfrag[t][kh] = *(const half8*)(W2T + (size_t)(t * 16 + mrow) * D_HID
                                               + kh * 32 + quad * 8);
    float bias[4];
#pragma unroll
    for (int t = 0; t < 4; ++t) bias[t] = b2[t * 16 + mrow];

    // fine bucketing into LDS: each thread walks 2 sort-block segments.
    for (int i = tid; i < NPB; i += 256) lcnt[i] = 0;
    __syncthreads();
    for (int seg = tid; seg < B1; seg += 256) {
        const int s0 = dir[(size_t)seg * NBKT + bkt];
        const int s1 = (bkt + 1 < NBKT) ? dir[(size_t)seg * NBKT + bkt + 1]
                                        : (seg + 1) * E_PER_B1;
        for (int j = s0; j < s1; ++j) {
            unsigned enc = coarse[j];
            int local = (int)(enc & 31u);
            int s     = (int)(enc >> 5);
            int p = atomicAdd(&lcnt[local], 1);
            if (p < CAP) lslots[local][p] = s;
        }
    }
    __syncthreads();

    // per-node aggregation, 8 nodes per wave
    for (int ln = wave; ln < NPB; ln += 4) {
        const int node = nbase + ln;       // 3125*32 == N_NODES: no bound check

        const uint4 nq0 = *(const uint4*)(qb + (size_t)node * D_HID + quad * 8);
        const uint4 nq1 = *(const uint4*)(qb + (size_t)node * D_HID + 32 + quad * 8);

        int deg = lcnt[ln];
        if (deg > CAP) deg = CAP;
        const int rows = deg + 1;              // + self-loop
        const int nbat = (rows + 15) >> 4;

        float rmax[4][4];
#pragma unroll
        for (int t = 0; t < 4; ++t)
#pragma unroll
            for (int r = 0; r < 4; ++r) rmax[t][r] = -INFINITY;

        for (int b = 0; b < nbat; ++b) {
            int idx = b * 16 + mrow;
            int idxc = (idx < CAP) ? idx : (CAP - 1);    // clamp LDS read
            int s = (idx < deg) ? lslots[ln][idxc] : node;

            const uint4 v0 = *(const uint4*)(vb + (size_t)s * D_HID + quad * 8);
            const uint4 v1 = *(const uint4*)(vb + (size_t)s * D_HID + 32 + quad * 8);

            uint4 a0u, a1u;
            a0u.x = pk_subrelu(v0.x, nq0.x);
            a0u.y = pk_subrelu(v0.y, nq0.y);
            a0u.z = pk_subrelu(v0.z, nq0.z);
            a0u.w = pk_subrelu(v0.w, nq0.w);
            a1u.x = pk_subrelu(v1.x, nq1.x);
            a1u.y = pk_subrelu(v1.y, nq1.y);
            a1u.z = pk_subrelu(v1.z, nq1.z);
            a1u.w = pk_subrelu(v1.w, nq1.w);
            half8 a0 = __builtin_bit_cast(half8, a0u);
            half8 a1 = __builtin_bit_cast(half8, a1u);

#pragma unroll
            for (int t = 0; t < 4; ++t) {
                f32x4 acc = (f32x4){0.f, 0.f, 0.f, 0.f};
                acc = __builtin_amdgcn_mfma_f32_16x16x32_f16(a0, bfrag[t][0], acc, 0, 0, 0);
                acc = __builtin_amdgcn_mfma_f32_16x16x32_f16(a1, bfrag[t][1], acc, 0, 0, 0);
#pragma unroll
                for (int r = 0; r < 4; ++r)
                    rmax[t][r] = fmaxf(rmax[t][r], acc[r]);
            }
        }

        float fin[4];
#pragma unroll
        for (int t = 0; t < 4; ++t) {
            float m = fmaxf(fmaxf(rmax[t][0], rmax[t][1]), fmaxf(rmax[t][2], rmax[t][3]));
            m = fmaxf(m, __shfl_xor(m, 16, 64));
            m = fmaxf(m, __shfl_xor(m, 32, 64));
            fin[t] = m + bias[t];
        }
        float r = (quad == 0) ? fin[0] : (quad == 1) ? fin[1] : (quad == 2) ? fin[2] : fin[3];
        out[(size_t)node * D_OUT + lane] = r;
    }
}

// ---------------------------------------------------------------------------
extern "C" void kernel_launch(void* const* d_in, const int* in_sizes, int n_in,
                              void* d_out, int out_size, void* d_ws, size_t ws_size,
                              hipStream_t stream) {
    const float* x   = (const float*)d_in[0];
    const float* pos = (const float*)d_in[1];
    const int*   ei  = (const int*)d_in[2];   // [2][N_EDGES]: row0=src, row1=dst
    const float* W1  = (const float*)d_in[3];
    const float* b1  = (const float*)d_in[4];
    const float* W2  = (const float*)d_in[5];
    const float* b2  = (const float*)d_in[6];
    float* out = (float*)d_out;

    char* ws = (char*)d_ws;
    unsigned short* vb   = (unsigned short*)ws;                     // 12.8 MB (f16 v)
    unsigned short* qb   = (unsigned short*)(ws + 12800000);        // 12.8 MB (f16 -q)
    unsigned int* coarse = (unsigned int*)(ws + 25600000);          // 6.4 MB
    int*            dir  = (int*)(ws + 32000000);                   // 6.4 MB (512x3125)
    unsigned short* W2T  = (unsigned short*)(ws + 38400000);        // 8 KB (f16, transposed)

    const int* src = ei;
    const int* dst = ei + N_EDGES;

    hipLaunchKernelGGL(sort_kernel, dim3(B1), dim3(1024), 0, stream,
                       src, dst, coarse, dir, W2, W2T);
    hipLaunchKernelGGL(node_kernel, dim3(NB_NODE), dim3(256), 0, stream,
                       x, pos, W1, b1, vb, qb);
    hipLaunchKernelGGL(agg_kernel, dim3(NBKT), dim3(256), 0, stream,
                       vb, qb, W2T, b2, dir, coarse, out);
}

// Round 15
// 182.120 us; speedup vs baseline: 1.1016x; 1.0385x over previous
//
#include <hip/hip_runtime.h>
#include <math.h>

#define N_NODES 100000
#define N_EDGES 1600000
#define D_FEAT 32
#define D_HID 64
#define D_OUT 64
#define CAP 48          // per-node slot capacity; deg ~ Poisson(16), safe
#define NPB 32          // nodes per coarse bucket (1<<5); 3125*32 = 100000 exact
#define NBKT 3125       // N_NODES / NPB
#define B1 256          // sort blocks (R14 lesson: 512 segments bloat agg's
                        // dir/segment reads, FETCH +14MB, agg +6us. 256 it is.)
#define E_PER_B1 6250   // 256 * 6250 = 1.6M edges exactly
#define NTILE 64        // node-precompute tile (64 nodes staged in LDS)
#define NB_NODE 1563    // ceil(100000/64) node tiles, one block each

typedef _Float16 half8 __attribute__((ext_vector_type(8)));
typedef float f32x4  __attribute__((ext_vector_type(4)));

// packed f16 relu(v + (-q)) on a channel pair, guaranteed lowering:
// exactly one v_pk_add_f16 + one v_pk_max_f16.
__device__ inline unsigned pk_subrelu(unsigned v, unsigned nq) {
    unsigned r;
    asm("v_pk_add_f16 %0, %1, %2\n\t"
        "v_pk_max_f16 %0, %0, 0"
        : "=v"(r) : "v"(v), "v"(nq));
    return r;
}

// ---------------------------------------------------------------------------
// Kernel 1: per-node precompute (R11-identical; f32 math, f16 store, q
// NEGATED). 64-node x/pos tiles staged into LDS with coalesced loads; the
// per-node x reads are LDS broadcasts instead of 35 serial uniform VMEM ops.
// ---------------------------------------------------------------------------
__global__ __launch_bounds__(256)
void node_kernel(const float* __restrict__ x,
                 const float* __restrict__ pos,
                 const float* __restrict__ W1,
                 const float* __restrict__ b1,
                 unsigned short* __restrict__ vb,
                 unsigned short* __restrict__ qb) {
    __shared__ float xs[NTILE * D_FEAT];   // 8 KB
    __shared__ float ps[NTILE * 3];        // 768 B

    const int tid  = threadIdx.x;
    const int lane = tid & 63;
    const int wave = tid >> 6;

    const int n0  = blockIdx.x * NTILE;
    const int cnt = (N_NODES - n0 < NTILE) ? (N_NODES - n0) : NTILE;  // 64 or 32

    for (int i = tid; i < cnt * D_FEAT; i += 256)
        xs[i] = x[(size_t)n0 * D_FEAT + i];
    for (int i = tid; i < cnt * 3; i += 256)
        ps[i] = pos[(size_t)n0 * 3 + i];

    float w[D_FEAT + 3];
#pragma unroll
    for (int f = 0; f < D_FEAT + 3; ++f)
        w[f] = W1[f * D_HID + lane];
    const float bb = b1[lane];
    __syncthreads();

    for (int ln = wave; ln < cnt; ln += 4) {
        const int node = n0 + ln;
        float acc = bb;
#pragma unroll
        for (int f = 0; f < D_FEAT; ++f)
            acc = fmaf(xs[ln * D_FEAT + f], w[f], acc);   // LDS broadcast reads

        float qa = 0.0f;
#pragma unroll
        for (int p = 0; p < 3; ++p)
            qa = fmaf(ps[ln * 3 + p], w[D_FEAT + p], qa);

        vb[(size_t)node * D_HID + lane] =
            __builtin_bit_cast(unsigned short, (_Float16)(acc + qa));
        qb[(size_t)node * D_HID + lane] =
            __builtin_bit_cast(unsigned short, (_Float16)(-qa));
    }
}

// ---------------------------------------------------------------------------
// Kernel 2: dense local counting sort + W2T build (block 0) — R11-exact.
// dir is written DENSE (contiguous 12.5KB per block); the transpose to
// dirT (which agg prefers: measured agg 74.4us w/ dirT vs 82 w/ dense)
// is done by a separate tiny tiled-transpose kernel — taking R8's agg win
// without R8's scattered dirT-write cost on the sort side.
// Entry packing: (src << 5) | (dst & 31).
// ---------------------------------------------------------------------------
__global__ __launch_bounds__(1024)
void sort_kernel(const int* __restrict__ src,
                 const int* __restrict__ dst,
                 unsigned int* __restrict__ coarse,
                 int* __restrict__ dir,
                 const float* __restrict__ W2,
                 unsigned short* __restrict__ W2T) {
    __shared__ int hist[NBKT];       // 12.5 KB: counts -> starts -> cursors
    __shared__ int stage[E_PER_B1];  // 25 KB
    __shared__ int wsum[16];

    const int tid  = threadIdx.x;
    const int lane = tid & 63;
    const int wv   = tid >> 6;       // 0..15
    const int e0   = blockIdx.x * E_PER_B1;

    if (blockIdx.x == 0) {           // f16 transpose of W2 (16 KB, L2-hot)
        for (int i = tid; i < D_HID * D_OUT; i += 1024) {
            float w = W2[i];                      // i = k*64 + n
            W2T[(size_t)(i & 63) * D_HID + (i >> 6)] =
                __builtin_bit_cast(unsigned short, (_Float16)w);
        }
    }

    for (int b = tid; b < NBKT; b += 1024) hist[b] = 0;
    __syncthreads();

    for (int e = e0 + tid; e < e0 + E_PER_B1; e += 1024)
        atomicAdd(&hist[dst[e] >> 5], 1);
    __syncthreads();

    // ---- exclusive scan of hist (3125) in place: 4 elems/thread ----
    const int i0 = tid * 4;
    int c[4];
    int sum = 0;
#pragma unroll
    for (int k = 0; k < 4; ++k) {
        c[k] = (i0 + k < NBKT) ? hist[i0 + k] : 0;
        sum += c[k];
    }
    int inc = sum;                       // wave-inclusive scan of chunk sums
#pragma unroll
    for (int d = 1; d < 64; d <<= 1) {
        int u = __shfl_up(inc, d, 64);
        if (lane >= d) inc += u;
    }
    if (lane == 63) wsum[wv] = inc;      // wave totals
    __syncthreads();
    if (wv == 0) {
        int s = (lane < 16) ? wsum[lane] : 0;
#pragma unroll
        for (int d = 1; d < 16; d <<= 1) {
            int u = __shfl_up(s, d, 64);
            if (lane >= d) s += u;
        }
        if (lane < 16) wsum[lane] = s;   // inclusive wave prefix
    }
    __syncthreads();
    int excl = inc - sum + ((wv > 0) ? wsum[wv - 1] : 0);
#pragma unroll
    for (int k = 0; k < 4; ++k) {
        if (i0 + k < NBKT) hist[i0 + k] = excl;   // own slots only: no race
        excl += c[k];
    }
    __syncthreads();

    // ---- dense directory: absolute start of each bucket in this segment
    for (int b = tid; b < NBKT; b += 1024)
        dir[(size_t)blockIdx.x * NBKT + b] = e0 + hist[b];
    __syncthreads();                     // dir written before cursors move

    // ---- placement via LDS cursors into LDS staging ----
    for (int e = e0 + tid; e < e0 + E_PER_B1; e += 1024) {
        int d = dst[e], s = src[e];
        int p = atomicAdd(&hist[d >> 5], 1);   // p in [0, 6250) by construction
        stage[p] = (int)(((unsigned)s << 5) | (unsigned)(d & 31));
    }
    __syncthreads();

    // ---- dense, full-line copy-out ----
    for (int i = tid; i < E_PER_B1; i += 1024)
        coarse[e0 + i] = (unsigned)stage[i];
}

// ---------------------------------------------------------------------------
// Kernel 2b: tiled transpose dir[256][3125] -> dirT[3125][256].
// 6.4 MB coalesced L2-resident traffic ~ 1-2us. 32x33 LDS tile (no bank
// conflicts), both global sides full-line.
// ---------------------------------------------------------------------------
__global__ __launch_bounds__(256)
void transpose_dir(const int* __restrict__ dir, int* __restrict__ dirT) {
    __shared__ int t[32][33];
    const int tc = blockIdx.x;        // bkt tile, 0..97
    const int tr = blockIdx.y;        // blk tile, 0..7
    const int lx = threadIdx.x & 31;
    const int ly = threadIdx.x >> 5;  // 0..7
    const int c0 = tc * 32, r0 = tr * 32;
#pragma unroll
    for (int i = 0; i < 4; ++i) {
        int r = r0 + ly + i * 8;          // blk index (< 256 always)
        int c = c0 + lx;                  // bkt index
        if (c < NBKT)
            t[ly + i * 8][lx] = dir[(size_t)r * NBKT + c];
    }
    __syncthreads();
#pragma unroll
    for (int i = 0; i < 4; ++i) {
        int c = c0 + ly + i * 8;          // bkt index
        int r = r0 + lx;                  // blk index
        if (c < NBKT)
            dirT[(size_t)c * B1 + r] = t[lx][ly + i * 8];
    }
}

// ---------------------------------------------------------------------------
// Kernel 3: fused fine-bucketing + per-node MFMA aggregation — R11 body with
// the R8 dirT read (dense 1KB rows; measured 74.4us/FETCH 117MB vs dense-dir
// 82us/128MB). 3125 blocks of 256 thr, 8 nodes/wave, W2T vector prologue,
// packed-f16 afrag, 4x2 mfma_f32_16x16x32_f16, register max, coalesced
// store. Padding rows use src = i (self-loop, idempotent under max).
// ---------------------------------------------------------------------------
__global__ __launch_bounds__(256)
void agg_kernel(const unsigned short* __restrict__ vb,
                const unsigned short* __restrict__ qb,
                const unsigned short* __restrict__ W2T,
                const float* __restrict__ b2,
                const int* __restrict__ dirT,
                const unsigned int* __restrict__ coarse,
                float* __restrict__ out) {
    __shared__ int lcnt[NPB];
    __shared__ int lslots[NPB][CAP];

    const int tid  = threadIdx.x;
    const int lane = tid & 63;
    const int wave = tid >> 6;             // 0..3
    const int quad = lane >> 4;
    const int mrow = lane & 15;
    const int bkt  = blockIdx.x;
    const int nbase = bkt << 5;

    // B fragments: one 16B vector load each from W2T[n][k]
    half8 bfrag[4][2];
#pragma unroll
    for (int t = 0; t < 4; ++t)
#pragma unroll
        for (int kh = 0; kh < 2; ++kh)
            bfrag[t][kh] = *(const half8*)(W2T + (size_t)(t * 16 + mrow) * D_HID
                                               + kh * 32 + quad * 8);
    float bias[4];
#pragma unroll
    for (int t = 0; t < 4; ++t) bias[t] = b2[t * 16 + mrow];

    // fine bucketing into LDS: thread t walks sort-block t's segment.
    // Segment bounds come from two DENSE dirT rows (1 KB each).
    for (int i = tid; i < NPB; i += 256) lcnt[i] = 0;
    __syncthreads();
    {
        const int s0 = dirT[(size_t)bkt * B1 + tid];
        const int s1 = (bkt + 1 < NBKT) ? dirT[(size_t)(bkt + 1) * B1 + tid]
                                        : (tid + 1) * E_PER_B1;
        for (int j = s0; j < s1; ++j) {
            unsigned enc = coarse[j];
            int local = (int)(enc & 31u);
            int s     = (int)(enc >> 5);
            int p = atomicAdd(&lcnt[local], 1);
            if (p < CAP) lslots[local][p] = s;
        }
    }
    __syncthreads();

    // per-node aggregation, 8 nodes per wave
    for (int ln = wave; ln < NPB; ln += 4) {
        const int node = nbase + ln;       // 3125*32 == N_NODES: no bound check

        const uint4 nq0 = *(const uint4*)(qb + (size_t)node * D_HID + quad * 8);
        const uint4 nq1 = *(const uint4*)(qb + (size_t)node * D_HID + 32 + quad * 8);

        int deg = lcnt[ln];
        if (deg > CAP) deg = CAP;
        const int rows = deg + 1;              // + self-loop
        const int nbat = (rows + 15) >> 4;

        float rmax[4][4];
#pragma unroll
        for (int t = 0; t < 4; ++t)
#pragma unroll
            for (int r = 0; r < 4; ++r) rmax[t][r] = -INFINITY;

        for (int b = 0; b < nbat; ++b) {
            int idx = b * 16 + mrow;
            int idxc = (idx < CAP) ? idx : (CAP - 1);    // clamp LDS read
            int s = (idx < deg) ? lslots[ln][idxc] : node;

            const uint4 v0 = *(const uint4*)(vb + (size_t)s * D_HID + quad * 8);
            const uint4 v1 = *(const uint4*)(vb + (size_t)s * D_HID + 32 + quad * 8);

            uint4 a0u, a1u;
            a0u.x = pk_subrelu(v0.x, nq0.x);
            a0u.y = pk_subrelu(v0.y, nq0.y);
            a0u.z = pk_subrelu(v0.z, nq0.z);
            a0u.w = pk_subrelu(v0.w, nq0.w);
            a1u.x = pk_subrelu(v1.x, nq1.x);
            a1u.y = pk_subrelu(v1.y, nq1.y);
            a1u.z = pk_subrelu(v1.z, nq1.z);
            a1u.w = pk_subrelu(v1.w, nq1.w);
            half8 a0 = __builtin_bit_cast(half8, a0u);
            half8 a1 = __builtin_bit_cast(half8, a1u);

#pragma unroll
            for (int t = 0; t < 4; ++t) {
                f32x4 acc = (f32x4){0.f, 0.f, 0.f, 0.f};
                acc = __builtin_amdgcn_mfma_f32_16x16x32_f16(a0, bfrag[t][0], acc, 0, 0, 0);
                acc = __builtin_amdgcn_mfma_f32_16x16x32_f16(a1, bfrag[t][1], acc, 0, 0, 0);
#pragma unroll
                for (int r = 0; r < 4; ++r)
                    rmax[t][r] = fmaxf(rmax[t][r], acc[r]);
            }
        }

        float fin[4];
#pragma unroll
        for (int t = 0; t < 4; ++t) {
            float m = fmaxf(fmaxf(rmax[t][0], rmax[t][1]), fmaxf(rmax[t][2], rmax[t][3]));
            m = fmaxf(m, __shfl_xor(m, 16, 64));
            m = fmaxf(m, __shfl_xor(m, 32, 64));
            fin[t] = m + bias[t];
        }
        float r = (quad == 0) ? fin[0] : (quad == 1) ? fin[1] : (quad == 2) ? fin[2] : fin[3];
        out[(size_t)node * D_OUT + lane] = r;
    }
}

// ---------------------------------------------------------------------------
extern "C" void kernel_launch(void* const* d_in, const int* in_sizes, int n_in,
                              void* d_out, int out_size, void* d_ws, size_t ws_size,
                              hipStream_t stream) {
    const float* x   = (const float*)d_in[0];
    const float* pos = (const float*)d_in[1];
    const int*   ei  = (const int*)d_in[2];   // [2][N_EDGES]: row0=src, row1=dst
    const float* W1  = (const float*)d_in[3];
    const float* b1  = (const float*)d_in[4];
    const float* W2  = (const float*)d_in[5];
    const float* b2  = (const float*)d_in[6];
    float* out = (float*)d_out;

    char* ws = (char*)d_ws;
    unsigned short* vb   = (unsigned short*)ws;                     // 12.8 MB (f16 v)
    unsigned short* qb   = (unsigned short*)(ws + 12800000);        // 12.8 MB (f16 -q)
    unsigned int* coarse = (unsigned int*)(ws + 25600000);          // 6.4 MB
    int*            dir  = (int*)(ws + 32000000);                   // 3.2 MB (dense)
    int*            dirT = (int*)(ws + 35200000);                   // 3.2 MB (transposed)
    unsigned short* W2T  = (unsigned short*)(ws + 38400000);        // 8 KB (f16)

    const int* src = ei;
    const int* dst = ei + N_EDGES;

    hipLaunchKernelGGL(sort_kernel, dim3(B1), dim3(1024), 0, stream,
                       src, dst, coarse, dir, W2, W2T);
    hipLaunchKernelGGL(transpose_dir, dim3(98, 8), dim3(256), 0, stream,
                       dir, dirT);
    hipLaunchKernelGGL(node_kernel, dim3(NB_NODE), dim3(256), 0, stream,
                       x, pos, W1, b1, vb, qb);
    hipLaunchKernelGGL(agg_kernel, dim3(NBKT), dim3(256), 0, stream,
                       vb, qb, W2T, b2, dirT, coarse, out);
}